// Round 5
// baseline (578.540 us; speedup 1.0000x reference)
//
#include <hip/hip_runtime.h>
#include <hip/hip_cooperative_groups.h>
#include <math.h>

namespace cg = cooperative_groups;

constexpr int Bn   = 32;
constexpr int L    = 65536;            // T*K
constexpr int NCH  = 6;
constexpr int SPAN = 256;              // hexads per span (64 lanes x 4 iters)
constexpr int NS   = L / SPAN;         // 256 spans per batch row
constexpr int ROW  = L * NCH;
constexpr int EPW_ROW = (L - 1) * NCH;
constexpr int NSPAN = Bn * NS;         // 8192 spans
constexpr int NBLK  = 1024;            // 4096 waves, 2 spans per wave
constexpr float AF = 0.99999f;         // a = 1 - theta*dt
constexpr float DS_ACC  = 0.2f   * 0.004472135954999579f;
constexpr float DS_GYRO = 0.015f * 0.004472135954999579f;

// a^(lane+1) and a^(63-lane), double-accurate
__device__ __forceinline__ void lane_pows(int lane, float& ap1, float& arev) {
    const double a = (double)AF;
    double t = a, p1 = 1.0, pr = 1.0;
    int e1 = lane + 1, er = 63 - lane;
    #pragma unroll
    for (int k = 0; k < 7; ++k) {
        if (e1 & (1 << k)) p1 *= t;
        if (er & (1 << k)) pr *= t;
        t *= t;
    }
    ap1 = (float)p1; arev = (float)pr;
}

// dense (lane<->hexad) load of one scaled-innovation hexad at step l
__device__ __forceinline__ void load_x(const float* __restrict__ epw,
                                       const float* __restrict__ eps0,
                                       int b, int l, float x[6]) {
    int lm1 = (l == 0) ? 0 : l - 1;
    const float2* p = (const float2*)(epw + (size_t)b * EPW_ROW + (size_t)lm1 * NCH);
    float2 v0 = p[0], v1 = p[1], v2 = p[2];
    x[0] = v0.x * DS_ACC;  x[1] = v0.y * DS_ACC;  x[2] = v1.x * DS_ACC;
    x[3] = v1.y * DS_GYRO; x[4] = v2.x * DS_GYRO; x[5] = v2.y * DS_GYRO;
    if (l == 0) {
        const float* e0 = eps0 + b * NCH;
        x[0] = e0[0] * 0.2f;   x[1] = e0[1] * 0.2f;   x[2] = e0[2] * 0.2f;
        x[3] = e0[3] * 0.015f; x[4] = e0[4] * 0.015f; x[5] = e0[5] * 0.015f;
    }
}

// ---- phase 1 helper: span weighted total -> part[chain][NS] (36 shuffles) ----
__device__ __forceinline__ void span_partial(const float* __restrict__ epw,
                                             const float* __restrict__ eps0,
                                             float* __restrict__ part,
                                             int sp, int lane, float arev, float A64) {
    int b = sp >> 8, s = sp & (NS - 1);
    int l0 = s * SPAN;
    float t[6] = {0.f, 0.f, 0.f, 0.f, 0.f, 0.f};
    #pragma unroll
    for (int it = 0; it < 4; ++it) {
        float x[6]; load_x(epw, eps0, b, l0 + it * 64 + lane, x);
        #pragma unroll
        for (int c = 0; c < 6; ++c) t[c] = fmaf(A64, t[c], x[c]);
    }
    float z0, z1, z2, z3, z4, z5;
    float* zp[6] = {&z0, &z1, &z2, &z3, &z4, &z5};
    #pragma unroll
    for (int c = 0; c < 6; ++c) {
        float z = arev * t[c];
        #pragma unroll
        for (int m = 1; m < 64; m <<= 1) z += __shfl_xor(z, m, 64);
        *zp[c] = z;
    }
    if (lane < 6) {
        float v = z0;
        if (lane == 1) v = z1; else if (lane == 2) v = z2;
        else if (lane == 3) v = z3; else if (lane == 4) v = z4;
        else if (lane == 5) v = z5;
        part[((size_t)(b * NCH + lane)) * NS + s] = v;
    }
}

// ---- phase 3 helper: fused scan + elementwise for one span (proven 52us) ----
__device__ __forceinline__ void span_apply(const float* __restrict__ imu,
                                           const float* __restrict__ eps0,
                                           const float* __restrict__ epw,
                                           const float* __restrict__ mn,
                                           const float* __restrict__ carry,
                                           float* __restrict__ out,
                                           int sp, int lane, float ap1) {
    int b = sp >> 8, s = sp & (NS - 1);
    int l0 = s * SPAN;
    float e[6];
    #pragma unroll
    for (int c = 0; c < 6; ++c) e[c] = carry[(size_t)sp * NCH + c];

    const float inv = 1.0f / 65535.0f, twopi = 6.283185307179586f;
    #pragma unroll
    for (int it = 0; it < 4; ++it) {
        int l = l0 + it * 64 + lane;
        float x[6]; load_x(epw, eps0, b, l, x);
        float bias[6];
        #pragma unroll
        for (int c = 0; c < 6; ++c) {
            float S = x[c], m = AF;
            #pragma unroll
            for (int d = 1; d < 64; d <<= 1) {
                float up = __shfl_up(S, d, 64);
                if (lane >= d) S = fmaf(m, up, S);
                m *= m;
            }
            bias[c] = fmaf(ap1, e[c], S);
            e[c] = __shfl(bias[c], 63, 64);
        }
        float tt = (float)l * inv;
        float temp = fmaf(5.0f, __sinf(twopi * tt), fmaf(2.0f, tt, 20.0f));
        float ta = temp * 0.001f, tg = temp * 0.01f;

        size_t roff = (size_t)b * ROW + (size_t)l * NCH;
        const float2* ip = (const float2*)(imu + roff);
        const float2* mp = (const float2*)(mn + roff);
        float2* op = (float2*)(out + roff);
        float2 i0 = ip[0], i1 = ip[1], i2 = ip[2];
        float2 m0 = mp[0], m1 = mp[1], m2 = mp[2];
        float2 o0, o1, o2;
        o0.x = i0.x + bias[0] + m0.x * 0.1f  + ta;
        o0.y = i0.y + bias[1] + m0.y * 0.1f  + ta;
        o1.x = i1.x + bias[2] + m1.x * 0.1f  + ta;
        o1.y = i1.y + bias[3] + m1.y * 0.01f + tg;
        o2.x = i2.x + bias[4] + m2.x * 0.01f + tg;
        o2.y = i2.y + bias[5] + m2.y * 0.01f + tg;
        op[0] = o0; op[1] = o1; op[2] = o2;
    }
}

// ---------------- single fused cooperative kernel ----------------
__global__ __launch_bounds__(256, 4) void k_fused(
    const float* __restrict__ imu,
    const float* __restrict__ eps0,
    const float* __restrict__ epw,
    const float* __restrict__ mn,
    float* __restrict__ out,
    float* __restrict__ part,     // [192][NS]
    float* __restrict__ carry)    // [NSPAN][6]
{
    cg::grid_group grid = cg::this_grid();
    int lane = threadIdx.x & 63;
    int wv = blockIdx.x * 4 + (threadIdx.x >> 6);   // 0..4095
    int sp0 = 2 * wv, sp1 = 2 * wv + 1;

    float ap1, arev; lane_pows(lane, ap1, arev);
    double a64d = (double)AF;
    #pragma unroll
    for (int k = 0; k < 6; ++k) a64d *= a64d;       // a^64
    const float A64 = (float)a64d;

    // ---- phase 1: span totals ----
    span_partial(epw, eps0, part, sp0, lane, arev, A64);
    span_partial(epw, eps0, part, sp1, lane, arev, A64);

    __threadfence();
    grid.sync();

    // ---- phase 2: 192 chain scans (waves 0..191) ----
    if (wv < Bn * NCH) {
        int chain = wv;                  // b*6 + c
        int b = chain / NCH, c = chain % NCH;
        double A = (double)AF;
        #pragma unroll
        for (int k = 0; k < 8; ++k) A *= A;   // a^256
        double A4 = A * A; A4 *= A4;          // a^1024 per-lane (4 spans)

        const float4* pp = (const float4*)(part + (size_t)chain * NS);
        float4 pv = pp[lane];
        double t = (double)pv.x;
        t = A * t + (double)pv.y; t = A * t + (double)pv.z; t = A * t + (double)pv.w;

        double I = t, m = A4;
        #pragma unroll
        for (int d = 1; d <= 32; d <<= 1) {
            double up = __shfl_up(I, d, 64);
            if (lane >= d) I = m * up + I;
            m = m * m;
        }
        double cin = __shfl_up(I, 1, 64);
        if (lane == 0) cin = 0.0;

        float pvv[4] = {pv.x, pv.y, pv.z, pv.w};
        double e = cin;
        #pragma unroll
        for (int k = 0; k < 4; ++k) {
            int s = lane * 4 + k;
            carry[((size_t)b * NS + s) * NCH + c] = (float)e;  // E_{s-1}
            e = A * e + (double)pvv[k];
        }
    }

    __threadfence();
    grid.sync();

    // ---- phase 3: fused scan + elementwise ----
    span_apply(imu, eps0, epw, mn, carry, out, sp0, lane, ap1);
    span_apply(imu, eps0, epw, mn, carry, out, sp1, lane, ap1);
}

extern "C" void kernel_launch(void* const* d_in, const int* in_sizes, int n_in,
                              void* d_out, int out_size, void* d_ws, size_t ws_size,
                              hipStream_t stream) {
    const float* imu  = (const float*)d_in[0];   // [B, L, 6]
    const float* eps0 = (const float*)d_in[1];   // [B, 6]
    const float* epw  = (const float*)d_in[2];   // [B, L-1, 6]
    const float* mn   = (const float*)d_in[3];   // [B, L, 6]
    float* out = (float*)d_out;

    float* part  = (float*)d_ws;                       // 192*NS floats
    float* carry = part + (size_t)Bn * NCH * NS;       // NSPAN*6 floats

    void* args[] = { (void*)&imu, (void*)&eps0, (void*)&epw, (void*)&mn,
                     (void*)&out, (void*)&part, (void*)&carry };
    hipLaunchCooperativeKernel((const void*)k_fused, dim3(NBLK), dim3(256),
                               args, 0, stream);
}